// Round 11
// baseline (354.470 us; speedup 1.0000x reference)
//
#include <hip/hip_runtime.h>
#include <math.h>

#define S_   2048
#define D_   1024
#define H_   16
#define DFF_ 4096

#define NEGINF (-__builtin_huge_valf())

typedef __bf16 bf16x8 __attribute__((ext_vector_type(8)));
typedef __bf16 bf16x4 __attribute__((ext_vector_type(4)));
typedef float  f32x4  __attribute__((ext_vector_type(4)));

static __device__ __forceinline__ unsigned short f2bf_rne(float f) {
    unsigned int u = __float_as_uint(f);
    u = (u + 0x7fffu + ((u >> 16) & 1u)) >> 16;
    return (unsigned short)u;
}

// ---------------- LayerNorm: one row (1024 floats) per 256-thread block ----------------
template<bool OBF>
__global__ __launch_bounds__(256) void ln_kernel(
    const float* __restrict__ x, const float* __restrict__ w,
    const float* __restrict__ b, void* __restrict__ y)
{
    const int row = blockIdx.x;
    const int t = threadIdx.x;
    const float4 v = reinterpret_cast<const float4*>(x + (size_t)row * D_)[t];
    float s  = v.x + v.y + v.z + v.w;
    float ss = v.x*v.x + v.y*v.y + v.z*v.z + v.w*v.w;
    #pragma unroll
    for (int o = 32; o; o >>= 1) {
        s  += __shfl_xor(s,  o, 64);
        ss += __shfl_xor(ss, o, 64);
    }
    __shared__ float red[8];
    const int wid = t >> 6, lane = t & 63;
    if (lane == 0) { red[wid] = s; red[4 + wid] = ss; }
    __syncthreads();
    s  = red[0] + red[1] + red[2] + red[3];
    ss = red[4] + red[5] + red[6] + red[7];
    const float mean = s * (1.f / D_);
    const float var  = ss * (1.f / D_) - mean * mean;
    const float rstd = rsqrtf(var + 1e-5f);
    const float4 wv = reinterpret_cast<const float4*>(w)[t];
    const float4 bv = reinterpret_cast<const float4*>(b)[t];
    float4 o;
    o.x = (v.x - mean) * rstd * wv.x + bv.x;
    o.y = (v.y - mean) * rstd * wv.y + bv.y;
    o.z = (v.z - mean) * rstd * wv.z + bv.z;
    o.w = (v.w - mean) * rstd * wv.w + bv.w;
    if (OBF) {
        ushort4 o4;
        o4.x = f2bf_rne(o.x); o4.y = f2bf_rne(o.y);
        o4.z = f2bf_rne(o.z); o4.w = f2bf_rne(o.w);
        reinterpret_cast<ushort4*>((unsigned short*)y + (size_t)row * D_)[t] = o4;
    } else {
        reinterpret_cast<float4*>((float*)y + (size_t)row * D_)[t] = o;
    }
}

// ---------------- Weight transpose + cast: fp32 [K][N] -> bf16 [N][K] ------------------
__global__ __launch_bounds__(256) void wcast_kernel(
    const float* __restrict__ in, unsigned short* __restrict__ outT, int K, int N)
{
    __shared__ float t[64][65];
    const int n0 = blockIdx.x * 64, k0 = blockIdx.y * 64;
    const int tid = threadIdx.x;
    #pragma unroll
    for (int i = 0; i < 16; ++i) {
        const int idx = i * 256 + tid;
        const int kk = idx >> 6, nn = idx & 63;
        t[kk][nn] = in[(size_t)(k0 + kk) * N + n0 + nn];
    }
    __syncthreads();
    #pragma unroll
    for (int i = 0; i < 16; ++i) {
        const int idx = i * 256 + tid;
        const int nn = idx >> 6, kk = idx & 63;
        outT[(size_t)(n0 + nn) * K + k0 + kk] = f2bf_rne(t[kk][nn]);
    }
}

// ---------------- bf16 MFMA GEMM: C[M,N] = A[M,K] @ Bt[N,K]^T (+bias, epi) -------------
// 128xBN tile, BK-step double-buffered staging via global_load_lds. BK=32 halves LDS
// (32 KB) -> 4 blocks/CU for LDS-capacity-capped shapes (FF1/QKV). BK=64 for grid-capped
// shapes. EPI==3 = split-K/2: one launch, 2x blocks; ks decoded AFTER the XCD swizzle
// (each XCD chunk stays in one K-half); raw fp32 partials to Cv (ks=0) / res (ks=1).
// Swizzle: source chunk ^= key(row), frag read chunk ^= key(frow); key = row&7 (BK=64)
// or (row>>1)&3 (BK=32; the row&3 variant leaves a 4-way bank conflict, this is 2-way).
template<int EPI, bool OBF, int BN, int BK>  // EPI 0:+bias 1:+bias,relu 2:+bias,+res 3:split-K raw
__global__ __launch_bounds__(256) void bgemm_kernel(
    const __bf16* __restrict__ A,   // [M][K] bf16
    const __bf16* __restrict__ Bt,  // [N][K] bf16 (pre-transposed)
    const float* __restrict__ bias, const float* __restrict__ res,
    void* __restrict__ Cv, int M, int N, int K)
{
    constexpr int RPI = 512 / BK;              // rows per gload_lds instr
    constexpr int NCH = BK / 8;                // 16B chunks per LDS row
    constexpr int AIT = 32 / RPI;              // A gloads per wave
    constexpr int BIT = (BN / 4) / RPI;        // B gloads per wave
    constexpr int MI  = (BN == 128) ? 4 : 2;   // 16-row frags per wave
    constexpr int KKN = BK / 32;               // MFMA k-chunks per step

    __shared__ __align__(16) __bf16 As[2][128 * BK];
    __shared__ __align__(16) __bf16 Bs[2][BN * BK];
    const int tid  = threadIdx.x;
    const int w    = tid >> 6, lane = tid & 63;
    const int wrow0 = (BN == 128) ? (w >> 1) * 64 : w * 32;
    const int wcol0 = (BN == 128) ? (w & 1) * 64 : 0;

    // XCD-aware bijective remap, then split-K decode
    const int lin = blockIdx.x;
    const int wg_full = (lin & 7) * (gridDim.x >> 3) + (lin >> 3);
    int wg = wg_full, ks = 0;
    if (EPI == 3) {
        const int half = gridDim.x >> 1;
        ks = wg_full >= half;
        wg = wg_full - ks * half;
    }
    const int gridM = M >> 7;
    const int col0 = (wg / gridM) * BN;
    const int row0 = (wg % gridM) << 7;
    const int Keff  = (EPI == 3) ? (K >> 1) : K;
    const int kbase = ks * Keff;

    const int srow   = lane / NCH;
    const int schunk = lane % NCH;
    const int swk_s  = (BK == 64) ? (srow & 7) : ((srow >> 1) & 3);
    const int scol   = (schunk ^ swk_s) * 8;
    const int frow   = lane & 15;
    const int l4     = lane >> 4;
    const int swk_r  = (BK == 64) ? (frow & 7) : ((frow >> 1) & 3);

    const __bf16* Abase = A  + (size_t)(row0 + srow) * K + kbase + scol;
    const __bf16* Bbase = Bt + (size_t)(col0 + srow) * K + kbase + scol;

    f32x4 acc[MI][4] = {};
    const int nt = Keff / BK;

    auto STAGE = [&](int bufi, int kt) {
        #pragma unroll
        for (int it = 0; it < AIT; ++it) {
            const int arow = w * 32 + it * RPI;
            __builtin_amdgcn_global_load_lds(
                (__attribute__((address_space(1))) void*)(Abase + (size_t)arow * K + kt),
                (__attribute__((address_space(3))) void*)(&As[bufi][arow * BK]), 16, 0, 0);
        }
        #pragma unroll
        for (int it = 0; it < BIT; ++it) {
            const int brow = w * (BN / 4) + it * RPI;
            __builtin_amdgcn_global_load_lds(
                (__attribute__((address_space(1))) void*)(Bbase + (size_t)brow * K + kt),
                (__attribute__((address_space(3))) void*)(&Bs[bufi][brow * BK]), 16, 0, 0);
        }
    };

    STAGE(0, 0);
    int buf = 0;
    for (int t = 0; t < nt; ++t) {
        __syncthreads();          // drains batch t (issued one compute-phase ago)
        if (t + 1 < nt) {         // prefetch next tile; latency hides under MFMA below
            STAGE(buf ^ 1, (t + 1) * BK);
        }
        #pragma unroll
        for (int kk = 0; kk < KKN; ++kk) {
            const int ch = ((kk * 4 + l4) ^ swk_r) * 8;
            bf16x8 af[MI], bfr[4];
            #pragma unroll
            for (int i = 0; i < MI; ++i)
                af[i] = *(const bf16x8*)&As[buf][(wrow0 + i * 16 + frow) * BK + ch];
            #pragma unroll
            for (int i = 0; i < 4; ++i)
                bfr[i] = *(const bf16x8*)&Bs[buf][(wcol0 + i * 16 + frow) * BK + ch];
            #pragma unroll
            for (int mi = 0; mi < MI; ++mi)
                #pragma unroll
                for (int ni = 0; ni < 4; ++ni)
                    acc[mi][ni] = __builtin_amdgcn_mfma_f32_16x16x32_bf16(
                        af[mi], bfr[ni], acc[mi][ni], 0, 0, 0);
        }
        buf ^= 1;
    }

    float bz[4] = {0.f, 0.f, 0.f, 0.f};
    if (EPI != 3) {
        #pragma unroll
        for (int ni = 0; ni < 4; ++ni) bz[ni] = bias[col0 + wcol0 + ni * 16 + frow];
    }
    float* Cd = (EPI == 3) ? (ks ? (float*)res : (float*)Cv) : (float*)Cv;
    #pragma unroll
    for (int mi = 0; mi < MI; ++mi) {
        #pragma unroll
        for (int j = 0; j < 4; ++j) {
            const int row = row0 + wrow0 + mi * 16 + l4 * 4 + j;
            #pragma unroll
            for (int ni = 0; ni < 4; ++ni) {
                const int col = col0 + wcol0 + ni * 16 + frow;
                float v = acc[mi][ni][j] + bz[ni];
                if (EPI == 1) v = fmaxf(v, 0.f);
                if (EPI == 2) v += res[(size_t)row * N + col];
                if (EPI == 3) Cd[(size_t)row * N + col] = v;
                else if (OBF) ((unsigned short*)Cv)[(size_t)row * N + col] = f2bf_rne(v);
                else          ((float*)Cv)[(size_t)row * N + col] = v;
            }
        }
    }
}

// ---------------- split-K combine: out = src2 + p0 + p1 + bias -------------------------
__global__ __launch_bounds__(256) void ksum_kernel(
    const float* __restrict__ p0, const float* __restrict__ p1,
    const float* __restrict__ s2, const float* __restrict__ bias,
    float* __restrict__ out)
{
    const int total = 4096 * 1024 / 4;      // float4 count
    const int stride = gridDim.x * 256;
    for (int i = blockIdx.x * 256 + threadIdx.x; i < total; i += stride) {
        const float4 a  = ((const float4*)p0)[i];
        const float4 b  = ((const float4*)p1)[i];
        const float4 s  = ((const float4*)s2)[i];
        const float4 bs = ((const float4*)bias)[i & 255];
        float4 o;
        o.x = s.x + a.x + b.x + bs.x;
        o.y = s.y + a.y + b.y + bs.y;
        o.z = s.z + a.z + b.z + bs.z;
        o.w = s.w + a.w + b.w + bs.w;
        ((float4*)out)[i] = o;
    }
}

// ---------------- bf16 MFMA flash attention with ALiBi, causal -------------------------
// Swapped QK^T (mfma(K,Q) -> S^T): each lane owns ONE query (l15), 16 score values.
// No max-tracking (scores bounded) + DEFERRED row-sum: zero per-step shuffles.
__global__ __launch_bounds__(256) void attn_kernel(
    const __bf16* __restrict__ qkv, __bf16* __restrict__ ctx)
{
    const int bh   = blockIdx.x & 31;
    const int qt   = 31 - (blockIdx.x >> 5);
    const int b    = bh >> 4, h = bh & 15;
    const int tid  = threadIdx.x;
    const int wid  = tid >> 6, lane = tid & 63;
    const int l15  = lane & 15, l4 = lane >> 4;
    const float slope2 = exp2f(-(float)h) * 1.44269504f;   // slope * log2(e)
    const size_t rowb = (size_t)b * S_;

    __shared__ __align__(16) __bf16 Ks[64 * 72];
    __shared__ __align__(16) __bf16 Vt[64 * 72];
    __shared__ __align__(16) __bf16 Ps[4 * 16 * 72];

    const int jr = tid >> 3;
    const int c  = tid & 7;
    const int c8 = c * 8;
    __bf16* psw = &Ps[wid * 16 * 72];
    const __bf16* base = qkv + rowb * 3072 + h * 64;

    const int i0 = qt << 6;

    bf16x8 qf[2];
    {
        const float QSC = 0.125f * 1.44269504f;
        const __bf16* qp = base + (size_t)(i0 + wid * 16 + l15) * 3072 + l4 * 8;
        bf16x8 r0 = *(const bf16x8*)(qp);
        bf16x8 r1 = *(const bf16x8*)(qp + 32);
        #pragma unroll
        for (int e = 0; e < 8; ++e) {
            qf[0][e] = (__bf16)((float)r0[e] * QSC);
            qf[1][e] = (__bf16)((float)r1[e] * QSC);
        }
    }

    float cb[4][4];
    #pragma unroll
    for (int ni = 0; ni < 4; ++ni)
        #pragma unroll
        for (int j = 0; j < 4; ++j)
            cb[ni][j] = slope2 * (float)(ni * 16 + l4 * 4 + j - wid * 16 - l15);

    float lsum = 0.f;
    f32x4 acc[4];
    #pragma unroll
    for (int ni = 0; ni < 4; ++ni) acc[ni] = (f32x4){0.f, 0.f, 0.f, 0.f};

    bf16x8 k0, k1, v0, v1;
    {   // prefetch tile 0
        const __bf16* kvp = base + (size_t)jr * 3072;
        k0 = *(const bf16x8*)(kvp + 1024 + c8);
        v0 = *(const bf16x8*)(kvp + 2048 + c8);
        k1 = *(const bf16x8*)(kvp + 32 * 3072 + 1024 + c8);
        v1 = *(const bf16x8*)(kvp + 32 * 3072 + 2048 + c8);
    }

    for (int kt = 0; kt <= qt; ++kt) {
        __syncthreads();
        *(bf16x8*)&Ks[jr * 72 + c8]        = k0;
        *(bf16x8*)&Ks[(jr + 32) * 72 + c8] = k1;
        const int sw0 = (((jr >> 3) ^ c) & 7) * 8 + (jr & 7);
        const int sw1 = ((((jr + 32) >> 3) ^ c) & 7) * 8 + (jr & 7);
        #pragma unroll
        for (int e = 0; e < 8; ++e) {
            Vt[(c8 + e) * 72 + sw0] = v0[e];
            Vt[(c8 + e) * 72 + sw1] = v1[e];
        }
        __syncthreads();

        if (kt < qt) {             // issue next tile's loads early (hide latency)
            const __bf16* kvp = base + (size_t)(((kt + 1) << 6) + jr) * 3072;
            k0 = *(const bf16x8*)(kvp + 1024 + c8);
            v0 = *(const bf16x8*)(kvp + 2048 + c8);
            k1 = *(const bf16x8*)(kvp + 32 * 3072 + 1024 + c8);
            v1 = *(const bf16x8*)(kvp + 32 * 3072 + 2048 + c8);
        }

        // ---- QK^T swapped: sf[ni] = S^T[key tile ni][query]; lane: key=l4*4+j, query=l15
        f32x4 sf[4];
        #pragma unroll
        for (int ni = 0; ni < 4; ++ni) sf[ni] = (f32x4){0.f, 0.f, 0.f, 0.f};
        #pragma unroll
        for (int kd = 0; kd < 2; ++kd)
            #pragma unroll
            for (int ni = 0; ni < 4; ++ni) {
                const bf16x8 kf = *(const bf16x8*)&Ks[(ni * 16 + l15) * 72 + kd * 32 + l4 * 8];
                sf[ni] = __builtin_amdgcn_mfma_f32_16x16x32_bf16(kf, qf[kd], sf[ni], 0, 0, 0);
            }

        // ---- softmax-lite: P = exp2(sf + bias2), no max-sub, per-lane deferred sum
        float p[4][4];
        if (kt == qt) {
            #pragma unroll
            for (int ni = 0; ni < 4; ++ni)
                #pragma unroll
                for (int j = 0; j < 4; ++j) {
                    const float e = (cb[ni][j] > 0.f)
                        ? 0.f
                        : __builtin_amdgcn_exp2f(sf[ni][j] + cb[ni][j]);
                    p[ni][j] = e;
                    lsum += e;
                }
        } else {
            const float dstep = slope2 * (float)((kt << 6) - i0);
            #pragma unroll
            for (int ni = 0; ni < 4; ++ni)
                #pragma unroll
                for (int j = 0; j < 4; ++j) {
                    const float e = __builtin_amdgcn_exp2f(sf[ni][j] + (cb[ni][j] + dstep));
                    p[ni][j] = e;
                    lsum += e;
                }
        }

        // ---- stage P [query][key]: 4x b64 writes (4 contiguous keys each)
        #pragma unroll
        for (int ni = 0; ni < 4; ++ni) {
            bf16x4 pk;
            pk[0] = (__bf16)p[ni][0]; pk[1] = (__bf16)p[ni][1];
            pk[2] = (__bf16)p[ni][2]; pk[3] = (__bf16)p[ni][3];
            *(bf16x4*)&psw[l15 * 72 + ni * 16 + l4 * 4] = pk;
        }
        asm volatile("" ::: "memory");

        // ---- PV: acc[query][d] += P @ V   (A=P[query][key], B=Vt[d][key])
        #pragma unroll
        for (int kk = 0; kk < 2; ++kk) {
            const bf16x8 pa = *(const bf16x8*)&psw[l15 * 72 + kk * 32 + l4 * 8];
            #pragma unroll
            for (int ni = 0; ni < 4; ++ni) {
                const int d = ni * 16 + l15;
                const int pc = ((kk * 4 + l4) ^ (d >> 3)) & 7;
                const bf16x8 bv = *(const bf16x8*)&Vt[d * 72 + pc * 8];
                acc[ni] = __builtin_amdgcn_mfma_f32_16x16x32_bf16(pa, bv, acc[ni], 0, 0, 0);
            }
        }
    }

    // ---- final l reduction: combine the 4 key-partitions of each query, broadcast
    lsum += __shfl_xor(lsum, 16, 64);
    lsum += __shfl_xor(lsum, 32, 64);
    float linv[4];
    #pragma unroll
    for (int j = 0; j < 4; ++j)
        linv[j] = 1.f / __shfl(lsum, l4 * 4 + j, 64);

    // ---- epilogue (acc layout: row=query=l4*4+j, col=d=ni*16+l15)
    #pragma unroll
    for (int ni = 0; ni < 4; ++ni) {
        const int col = h * 64 + ni * 16 + l15;
        #pragma unroll
        for (int j = 0; j < 4; ++j) {
            const int row = i0 + wid * 16 + l4 * 4 + j;
            ctx[(rowb + row) * (size_t)D_ + col] = (__bf16)(acc[ni][j] * linv[j]);
        }
    }
}

// ---------------- launch ----------------------------------------------------------------
extern "C" void kernel_launch(void* const* d_in, const int* in_sizes, int n_in,
                              void* d_out, int out_size, void* d_ws, size_t ws_size,
                              hipStream_t stream) {
    const float* src     = (const float*)d_in[0];
    const float* norm_w  = (const float*)d_in[1];
    const float* norm_b  = (const float*)d_in[2];
    const float* wqkv_w  = (const float*)d_in[3];
    const float* wqkv_b  = (const float*)d_in[4];
    const float* out_w   = (const float*)d_in[5];
    const float* out_b   = (const float*)d_in[6];
    const float* fnorm_w = (const float*)d_in[7];
    const float* fnorm_b = (const float*)d_in[8];
    const float* ff1_w   = (const float*)d_in[9];
    const float* ff1_b   = (const float*)d_in[10];
    const float* ff2_w   = (const float*)d_in[11];
    const float* ff2_b   = (const float*)d_in[12];
    float* out = (float*)d_out;

    const int M = 2 * S_;
    const size_t MB = 1u << 20;
    char* W = (char*)d_ws;
    // [0,6) wqkvT | [6,8) outT | [8,16) ff1T | [16,24) ff2T   (bf16 weights)
    // [24,32) h1/ctx bf16 | [32,40) h2 bf16 | [40,72) ffmid bf16 | [80,96) src2 fp32
    // split-K partials (live only during FF2+ksum): p0 [24,40), p1 [96,112)
    unsigned short* wqkvT = (unsigned short*)(W);
    unsigned short* outT  = (unsigned short*)(W + 6  * MB);
    unsigned short* ff1T  = (unsigned short*)(W + 8  * MB);
    unsigned short* ff2T  = (unsigned short*)(W + 16 * MB);
    unsigned short* h1    = (unsigned short*)(W + 24 * MB);
    unsigned short* qkv   = (unsigned short*)(W + 32 * MB);
    unsigned short* ctx   = (unsigned short*)(W + 24 * MB);
    unsigned short* h2    = (unsigned short*)(W + 32 * MB);
    unsigned short* ffmid = (unsigned short*)(W + 40 * MB);
    float*          src2  = (float*)        (W + 80 * MB);
    float*          p0    = (float*)        (W + 24 * MB);
    float*          p1    = (float*)        (W + 96 * MB);

    wcast_kernel<<<dim3(3072/64, 1024/64), 256, 0, stream>>>(wqkv_w, wqkvT, 1024, 3072);
    wcast_kernel<<<dim3(1024/64, 1024/64), 256, 0, stream>>>(out_w,  outT,  1024, 1024);
    wcast_kernel<<<dim3(4096/64, 1024/64), 256, 0, stream>>>(ff1_w,  ff1T,  1024, 4096);
    wcast_kernel<<<dim3(1024/64, 4096/64), 256, 0, stream>>>(ff2_w,  ff2T,  4096, 1024);

    // 1) h1 = LN(src) -> bf16
    ln_kernel<true><<<M, 256, 0, stream>>>(src, norm_w, norm_b, h1);
    // 2) qkv = h1 @ wqkv_w + wqkv_b -> bf16  [4096 x 3072]  (768 blocks, BK=32: 4/CU)
    bgemm_kernel<0, true, 128, 32><<<(3072/128) * (M/128), 256, 0, stream>>>(
        (const __bf16*)h1, (const __bf16*)wqkvT, wqkv_b, nullptr, qkv, M, 3072, 1024);
    // 3) ctx = flash-attn(q,k,v) -> bf16  (1024 blocks: 32 qt x 32 bh)
    attn_kernel<<<1024, 256, 0, stream>>>((const __bf16*)qkv, (__bf16*)ctx);
    // 4) src2 = src + ctx @ out_w + out_b  fp32  (512 blocks, BN=64, BK=64)
    bgemm_kernel<2, false, 64, 64><<<(1024/64) * (M/128), 256, 0, stream>>>(
        (const __bf16*)ctx, (const __bf16*)outT, out_b, src, src2, M, 1024, 1024);
    // 5) h2 = LN(src2) -> bf16
    ln_kernel<true><<<M, 256, 0, stream>>>(src2, fnorm_w, fnorm_b, h2);
    // 6) ffmid = relu(h2 @ ff1_w + ff1_b) -> bf16  [4096 x 4096]  (1024 blocks, BK=32: 4/CU)
    bgemm_kernel<1, true, 128, 32><<<(4096/128) * (M/128), 256, 0, stream>>>(
        (const __bf16*)h2, (const __bf16*)ff1T, ff1_b, nullptr, ffmid, M, 4096, 1024);
    // 7) split-K/2: p0/p1 = ffmid @ ff2_w (halves)  (1024 blocks)
    bgemm_kernel<3, false, 64, 64><<<2 * (1024/64) * (M/128), 256, 0, stream>>>(
        (const __bf16*)ffmid, (const __bf16*)ff2T, nullptr, p1, p0, M, 1024, 4096);
    // 8) out = src2 + p0 + p1 + ff2_b
    ksum_kernel<<<2048, 256, 0, stream>>>(p0, p1, src2, ff2_b, out);
}